// Round 10
// baseline (255.969 us; speedup 1.0000x reference)
//
#include <hip/hip_runtime.h>

#define T_SEQ 4096
#define BATCH 4
#define DD 128
#define BT (BATCH * T_SEQ)

typedef __bf16 bf16x8 __attribute__((ext_vector_type(8)));
typedef float f32x4 __attribute__((ext_vector_type(4)));

__device__ inline bf16x8 ld8(const unsigned short* p) {
  return *reinterpret_cast<const bf16x8*>(p);
}
__device__ inline unsigned short bfc(float f) {
  __bf16 v = (__bf16)f;
  return __builtin_bit_cast(unsigned short, v);
}

#define MFMA(a, b, c) __builtin_amdgcn_mfma_f32_16x16x32_bf16((a), (b), (c), 0, 0, 0)

// ---- W (128x128 f32, [d][u]) -> frag-major bf16:
// F[((n0*4+c)*64 + lane)*8 + j] = W[(c*32+g*8+j)*128 + n0*16+t], lane=(g<<4)|t.
__global__ void wt_kernel(const float* __restrict__ Wq, const float* __restrict__ Wk,
                          const float* __restrict__ Wv,
                          unsigned short* __restrict__ fq, unsigned short* __restrict__ fk,
                          unsigned short* __restrict__ fv) {
  const float* W = (blockIdx.y == 0) ? Wq : (blockIdx.y == 1) ? Wk : Wv;
  unsigned short* F = (blockIdx.y == 0) ? fq : (blockIdx.y == 1) ? fk : fv;
  int e = blockIdx.x * 256 + threadIdx.x;          // 0..16383
  int j = e & 7, lane = (e >> 3) & 63, nc = e >> 9;
  int c = nc & 3, n0 = nc >> 2;
  int t = lane & 15, g = lane >> 4;
  F[e] = bfc(W[(c * 32 + g * 8 + j) * 128 + n0 * 16 + t]);
}

// ---- projections, W-STATIONARY (known-good since round 8) ----
// qf[((tile16*4+c)*64 + (G<<4|m))*8 + e] = Q[tile16*16+m][c*32+G*8+e] * (1/64)
// kf[(((j32*2+i)*4+c)*64 + (G<<4|tp))*8 + e] = K[j32*32+4i+kappa(tp)][c*32+G*8+e]
// vt2: V[key][u] at chunk*4096 + (u>>4)*512 + ((kk>>3)*16 + (u&15))*8 + (kk&7)
__global__ __launch_bounds__(256) void proj_kernel(
    const float* __restrict__ X,
    const unsigned short* __restrict__ fq,
    const unsigned short* __restrict__ fk,
    const unsigned short* __restrict__ fv,
    unsigned short* __restrict__ qf,
    unsigned short* __restrict__ kf,
    unsigned short* __restrict__ vt) {
  const int tid = threadIdx.x;
  const int w = tid >> 6, lane = tid & 63;
  const int t = lane & 15, g = lane >> 4;
  const int r0 = blockIdx.x * 32;   // 512 blocks x 32 rows

  __shared__ unsigned short xs[2][16 * 136];

  bf16x8 wq[2][4], wk[2][4], wv[2][4];
#pragma unroll
  for (int s = 0; s < 2; ++s)
#pragma unroll
    for (int c = 0; c < 4; ++c) {
      int fo = (((w + s * 4) * 4 + c) * 64 + lane) * 8;
      wq[s][c] = ld8(fq + fo);
      wk[s][c] = ld8(fk + fo);
      wv[s][c] = ld8(fv + fo);
    }

#pragma unroll
  for (int sub = 0; sub < 2; ++sub) {
    int r = tid >> 4, cb = tid & 15;
    const float* xp = X + (size_t)(r0 + sub * 16 + r) * DD + cb * 8;
    float4 lo = *reinterpret_cast<const float4*>(xp);
    float4 hi = *reinterpret_cast<const float4*>(xp + 4);
    bf16x8 tmp;
    tmp[0] = (__bf16)lo.x; tmp[1] = (__bf16)lo.y; tmp[2] = (__bf16)lo.z; tmp[3] = (__bf16)lo.w;
    tmp[4] = (__bf16)hi.x; tmp[5] = (__bf16)hi.y; tmp[6] = (__bf16)hi.z; tmp[7] = (__bf16)hi.w;
    *reinterpret_cast<bf16x8*>(&xs[sub][r * 136 + cb * 8]) = tmp;
  }
  __syncthreads();

#pragma unroll
  for (int sub = 0; sub < 2; ++sub) {
    const int r0s = r0 + sub * 16;
    bf16x8 x[4];
#pragma unroll
    for (int c = 0; c < 4; ++c)
      x[c] = ld8(&xs[sub][t * 136 + c * 32 + g * 8]);

#pragma unroll
    for (int s = 0; s < 2; ++s) {
      const int n0 = w + s * 4;
      f32x4 aq = {0.f, 0.f, 0.f, 0.f}, ak = {0.f, 0.f, 0.f, 0.f};
#pragma unroll
      for (int c = 0; c < 4; ++c) {
        aq = MFMA(x[c], wq[s][c], aq);
        ak = MFMA(x[c], wk[s][c], ak);
      }
      const int cP = n0 >> 1;
      const int Gp = ((n0 & 1) << 1) | (t >> 3);
      const int ep = t & 7;
#pragma unroll
      for (int r = 0; r < 4; ++r) {
        int row = r0s + g * 4 + r;
        size_t qoff = ((size_t)((row >> 4) * 4 + cP) * 64 + ((Gp << 4) | (row & 15))) * 8 + ep;
        qf[qoff] = bfc(aq[r] * 0.015625f);   // fold 1/sqrt(4096)
        int tp = (row & 3) | (((row >> 3) & 3) << 2);
        size_t koff =
            ((size_t)(((row >> 5) * 2 + ((row >> 2) & 1)) * 4 + cP) * 64 + ((Gp << 4) | tp)) * 8 +
            ep;
        kf[koff] = bfc(ak[r]);
      }
    }

    const int key = r0s + t;
    const int kk = key & 31;
    const size_t vbase = (size_t)(key >> 5) * 4096 + (size_t)(kk >> 3) * 128 + (kk & 7);
#pragma unroll
    for (int s = 0; s < 2; ++s) {
      const int u0 = w + s * 4;
      f32x4 av = {0.f, 0.f, 0.f, 0.f};
#pragma unroll
      for (int c = 0; c < 4; ++c)
        av = MFMA(wv[s][c], x[c], av);
#pragma unroll
      for (int r = 0; r < 4; ++r)
        vt[vbase + (size_t)u0 * 512 + (g * 4 + r) * 8] = bfc(av[r]);
    }
  }
}

// ---- flash attention v10: 256 blocks x 4 waves. Block = 64-query group gamma.
// Wave = (tile-pair P, key-slice s): 32 q/wave (R6's proven ~150-reg footprint).
// Each iter stages TWO 16-KB chunks (slice0: 2i, slice1: 2i+1) into 64-KB
// double-buffered LDS; each chunk read by the 2 waves of its slice -> global
// traffic halved vs R6. Loads issued at loop top, ds_written at bottom,
// 1 barrier/iter. Slices combined in-block via LDS (buffer reused).
__global__ __launch_bounds__(256) void attn_kernel(
    const unsigned short* __restrict__ qf,
    const unsigned short* __restrict__ kf,
    const unsigned short* __restrict__ vt,
    float* __restrict__ out) {
  const int tid = threadIdx.x;
  const int w = tid >> 6, lane = tid & 63;
  const int t = lane & 15, G = lane >> 4;
  const int bi = blockIdx.x;
  const int xcd = bi & 7;                       // assumed round-robin XCD mapping
  const int b = xcd >> 1;                       // batch pinned to an XCD pair
  const int gi = ((bi >> 3) << 1) | (xcd & 1);  // 0..63 within batch
  const int gamma = 63 - gi;                    // biggest groups dispatch first
  const int q0 = gamma * 64;
  const int niter = gamma + 1;                  // chunk pairs
  const int P = w >> 1, s = w & 1;
  const int qbase = q0 + 32 * P;                // this wave's 32 queries

  const unsigned short* kfb = kf + (size_t)b * 128 * 4096;
  const unsigned short* vtb = vt + (size_t)b * 128 * 4096;

  __shared__ unsigned short buf[2][2][8192];    // [phase][slice][K 8KB | V 8KB]

  // Q fragments for tiles 4g+2P, 4g+2P+1: coalesced 1-KB loads
  bf16x8 qa[2][4];
#pragma unroll
  for (int X = 0; X < 2; ++X)
#pragma unroll
    for (int c = 0; c < 4; ++c)
      qa[X][c] =
          ld8(qf + ((size_t)((b * 256 + 4 * gamma + 2 * P + X) * 4 + c) * 64 + lane) * 8);

  f32x4 O[2][8];
#pragma unroll
  for (int X = 0; X < 2; ++X)
#pragma unroll
    for (int u0 = 0; u0 < 8; ++u0) O[X][u0] = (f32x4){0.f, 0.f, 0.f, 0.f};
  float ls[2] = {0.f, 0.f};

  // staging: thread covers 8 x 16B; k -> (slice k>>2, K/V (k>>1)&1, half k&1)
  // src = base[k>>1] + (((k&1)<<8) + tid)*8 shorts ; dst mirrors it in LDS.
  {
    const unsigned short* base0[4] = {kfb, vtb, kfb + 4096, vtb + 4096};  // chunks 0,1
#pragma unroll
    for (int k = 0; k < 8; ++k) {
      uint4 r = *reinterpret_cast<const uint4*>(base0[k >> 1] + (((k & 1) << 8) + tid) * 8);
      *reinterpret_cast<uint4*>(
          &buf[0][k >> 2][(((k >> 1) & 1) << 12) + (((k & 1) << 8) + tid) * 8]) = r;
    }
  }
  __syncthreads();

  for (int i = 0; i < niter; ++i) {
    // issue next pair's global loads first (latency hidden under compute)
    const bool hn = (i + 1) < niter;
    uint4 pre[8];
    if (hn) {
      const unsigned short* kA = kfb + (size_t)(2 * i + 2) * 4096;
      const unsigned short* vA = vtb + (size_t)(2 * i + 2) * 4096;
      const unsigned short* baseN[4] = {kA, vA, kA + 4096, vA + 4096};
#pragma unroll
      for (int k = 0; k < 8; ++k)
        pre[k] = *reinterpret_cast<const uint4*>(baseN[k >> 1] + (((k & 1) << 8) + tid) * 8);
    }

    // compute chunk j = 2i+s from buf[i&1][s]
    const int j0 = (2 * i + s) * 32;
    if (j0 <= qbase + 31) {                     // skip fully-masked chunk
      const unsigned short* kb = &buf[i & 1][s][0];
      const unsigned short* vb = &buf[i & 1][s][4096];

      f32x4 sA0 = (f32x4){0.f, 0.f, 0.f, 0.f}, sA1 = sA0, sB0 = sA0, sB1 = sA0;
#pragma unroll
      for (int c = 0; c < 4; ++c) {
        bf16x8 kc0 = ld8(kb + c * 512 + lane * 8);
        bf16x8 kc1 = ld8(kb + (4 + c) * 512 + lane * 8);
        sA0 = MFMA(kc0, qa[0][c], sA0);
        sA1 = MFMA(kc1, qa[0][c], sA1);
        sB0 = MFMA(kc0, qa[1][c], sB0);
        sB1 = MFMA(kc1, qa[1][c], sB1);
      }

      bf16x8 pbA, pbB;
      if (j0 + 31 <= qbase) {  // interior: no mask for either tile
#pragma unroll
        for (int r = 0; r < 4; ++r) {
          float a0 = __expf(sA0[r]), a1 = __expf(sA1[r]);
          float b0 = __expf(sB0[r]), b1 = __expf(sB1[r]);
          ls[0] += a0 + a1;
          ls[1] += b0 + b1;
          pbA[r] = (__bf16)a0; pbA[r + 4] = (__bf16)a1;
          pbB[r] = (__bf16)b0; pbB[r + 4] = (__bf16)b1;
        }
      } else {                 // diagonal: per-element causal mask
        const int limA = qbase + t, limB = qbase + 16 + t;
#pragma unroll
        for (int r = 0; r < 4; ++r) {
          int k0 = j0 + G * 8 + r;
          float a0 = (k0 <= limA) ? __expf(sA0[r]) : 0.f;
          float a1 = (k0 + 4 <= limA) ? __expf(sA1[r]) : 0.f;
          float b0 = (k0 <= limB) ? __expf(sB0[r]) : 0.f;
          float b1 = (k0 + 4 <= limB) ? __expf(sB1[r]) : 0.f;
          ls[0] += a0 + a1;
          ls[1] += b0 + b1;
          pbA[r] = (__bf16)a0; pbA[r + 4] = (__bf16)a1;
          pbB[r] = (__bf16)b0; pbB[r + 4] = (__bf16)b1;
        }
      }

#pragma unroll
      for (int u0 = 0; u0 < 8; ++u0) {
        bf16x8 vf = ld8(vb + u0 * 512 + lane * 8);
        O[0][u0] = MFMA(pbA, vf, O[0][u0]);
        O[1][u0] = MFMA(pbB, vf, O[1][u0]);
      }
    }

    if (hn) {
#pragma unroll
      for (int k = 0; k < 8; ++k)
        *reinterpret_cast<uint4*>(
            &buf[(i + 1) & 1][k >> 2][(((k >> 1) & 1) << 12) + (((k & 1) << 8) + tid) * 8]) =
            pre[k];
    }
    __syncthreads();
  }

  // in-block slice combine (partials add; no online max). Reuse buf as floats.
  float* cmb = reinterpret_cast<float*>(&buf[0][0][0]);  // [2][64][67] floats
  if (s == 1) {
    float* row = cmb + ((size_t)P * 64 + lane) * 67;
#pragma unroll
    for (int X = 0; X < 2; ++X)
#pragma unroll
      for (int u0 = 0; u0 < 8; ++u0)
        *reinterpret_cast<f32x4*>(row + X * 32 + u0 * 4) = O[X][u0];
    row[64] = ls[0];
    row[65] = ls[1];
  }
  __syncthreads();
  if (s == 0) {
    const float* row = cmb + ((size_t)P * 64 + lane) * 67;
#pragma unroll
    for (int X = 0; X < 2; ++X)
#pragma unroll
      for (int u0 = 0; u0 < 8; ++u0) {
        f32x4 q4 = *reinterpret_cast<const f32x4*>(row + X * 32 + u0 * 4);
        O[X][u0][0] += q4[0]; O[X][u0][1] += q4[1];
        O[X][u0][2] += q4[2]; O[X][u0][3] += q4[3];
      }
    ls[0] += row[64];
    ls[1] += row[65];
#pragma unroll
    for (int X = 0; X < 2; ++X) {
      // row sums: lanes {t,t+16,t+32,t+48} hold partials for query t of tile X
      float lt = ls[X];
      lt += __shfl_xor(lt, 16);
      lt += __shfl_xor(lt, 32);
      float linv[4];
#pragma unroll
      for (int r = 0; r < 4; ++r) linv[r] = 1.0f / __shfl(lt, G * 4 + r);
      float* op = out + ((size_t)(b * T_SEQ + qbase + 16 * X + G * 4)) * DD + t;
#pragma unroll
      for (int u0 = 0; u0 < 8; ++u0)
#pragma unroll
        for (int r = 0; r < 4; ++r)
          op[(size_t)r * DD + u0 * 16] = O[X][u0][r] * linv[r];
    }
  }
}

extern "C" void kernel_launch(void* const* d_in, const int* in_sizes, int n_in,
                              void* d_out, int out_size, void* d_ws, size_t ws_size,
                              hipStream_t stream) {
  const float* X  = (const float*)d_in[0];
  const float* Wq = (const float*)d_in[1];
  const float* Wk = (const float*)d_in[2];
  const float* Wv = (const float*)d_in[3];
  float* out = (float*)d_out;

  unsigned short* qf = (unsigned short*)d_ws;          // frag-major Q [BT/16][4][64][8]
  unsigned short* kf = qf + (size_t)BT * DD;            // frag-major K [BT/32][2][4][64][8]
  unsigned short* vt = kf + (size_t)BT * DD;            // vt2 V^T frag layout
  unsigned short* fq = vt + (size_t)BT * DD;            // frag-major W (16384 each)
  unsigned short* fk = fq + DD * DD;
  unsigned short* fv = fk + DD * DD;

  dim3 wt_grid(64, 3);
  wt_kernel<<<wt_grid, 256, 0, stream>>>(Wq, Wk, Wv, fq, fk, fv);
  proj_kernel<<<BT / 32, 256, 0, stream>>>(X, fq, fk, fv, qf, kf, vt);
  attn_kernel<<<256, 256, 0, stream>>>(qf, kf, vt, out);
}

// Round 11
// 116.061 us; speedup vs baseline: 2.2055x; 2.2055x over previous
//
#include <hip/hip_runtime.h>

#define T_SEQ 4096
#define BATCH 4
#define DD 128
#define BT (BATCH * T_SEQ)

typedef __bf16 bf16x8 __attribute__((ext_vector_type(8)));
typedef float f32x4 __attribute__((ext_vector_type(4)));

__device__ inline bf16x8 ld8(const unsigned short* p) {
  return *reinterpret_cast<const bf16x8*>(p);
}
__device__ inline unsigned short bfc(float f) {
  __bf16 v = (__bf16)f;
  return __builtin_bit_cast(unsigned short, v);
}

#define MFMA(a, b, c) __builtin_amdgcn_mfma_f32_16x16x32_bf16((a), (b), (c), 0, 0, 0)

// ---- W (128x128 f32, [d][u]) -> frag-major bf16:
// F[((n0*4+c)*64 + lane)*8 + j] = W[(c*32+g*8+j)*128 + n0*16+t], lane=(g<<4)|t.
__global__ void wt_kernel(const float* __restrict__ Wq, const float* __restrict__ Wk,
                          const float* __restrict__ Wv,
                          unsigned short* __restrict__ fq, unsigned short* __restrict__ fk,
                          unsigned short* __restrict__ fv) {
  const float* W = (blockIdx.y == 0) ? Wq : (blockIdx.y == 1) ? Wk : Wv;
  unsigned short* F = (blockIdx.y == 0) ? fq : (blockIdx.y == 1) ? fk : fv;
  int e = blockIdx.x * 256 + threadIdx.x;          // 0..16383
  int j = e & 7, lane = (e >> 3) & 63, nc = e >> 9;
  int c = nc & 3, n0 = nc >> 2;
  int t = lane & 15, g = lane >> 4;
  F[e] = bfc(W[(c * 32 + g * 8 + j) * 128 + n0 * 16 + t]);
}

// ---- projections, W-STATIONARY (known-good since round 8) ----
// qf[((tile16*4+c)*64 + (G<<4|m))*8 + e] = Q[tile16*16+m][c*32+G*8+e] * (1/64)
// kf[(((j32*2+i)*4+c)*64 + (G<<4|tp))*8 + e] = K[j32*32+4i+kappa(tp)][c*32+G*8+e]
// vt2: V[key][u] at chunk*4096 + (u>>4)*512 + ((kk>>3)*16 + (u&15))*8 + (kk&7)
__global__ __launch_bounds__(256) void proj_kernel(
    const float* __restrict__ X,
    const unsigned short* __restrict__ fq,
    const unsigned short* __restrict__ fk,
    const unsigned short* __restrict__ fv,
    unsigned short* __restrict__ qf,
    unsigned short* __restrict__ kf,
    unsigned short* __restrict__ vt) {
  const int tid = threadIdx.x;
  const int w = tid >> 6, lane = tid & 63;
  const int t = lane & 15, g = lane >> 4;
  const int r0 = blockIdx.x * 32;   // 512 blocks x 32 rows

  __shared__ unsigned short xs[2][16 * 136];

  bf16x8 wq[2][4], wk[2][4], wv[2][4];
#pragma unroll
  for (int s = 0; s < 2; ++s)
#pragma unroll
    for (int c = 0; c < 4; ++c) {
      int fo = (((w + s * 4) * 4 + c) * 64 + lane) * 8;
      wq[s][c] = ld8(fq + fo);
      wk[s][c] = ld8(fk + fo);
      wv[s][c] = ld8(fv + fo);
    }

#pragma unroll
  for (int sub = 0; sub < 2; ++sub) {
    int r = tid >> 4, cb = tid & 15;
    const float* xp = X + (size_t)(r0 + sub * 16 + r) * DD + cb * 8;
    float4 lo = *reinterpret_cast<const float4*>(xp);
    float4 hi = *reinterpret_cast<const float4*>(xp + 4);
    bf16x8 tmp;
    tmp[0] = (__bf16)lo.x; tmp[1] = (__bf16)lo.y; tmp[2] = (__bf16)lo.z; tmp[3] = (__bf16)lo.w;
    tmp[4] = (__bf16)hi.x; tmp[5] = (__bf16)hi.y; tmp[6] = (__bf16)hi.z; tmp[7] = (__bf16)hi.w;
    *reinterpret_cast<bf16x8*>(&xs[sub][r * 136 + cb * 8]) = tmp;
  }
  __syncthreads();

#pragma unroll
  for (int sub = 0; sub < 2; ++sub) {
    const int r0s = r0 + sub * 16;
    bf16x8 x[4];
#pragma unroll
    for (int c = 0; c < 4; ++c)
      x[c] = ld8(&xs[sub][t * 136 + c * 32 + g * 8]);

#pragma unroll
    for (int s = 0; s < 2; ++s) {
      const int n0 = w + s * 4;
      f32x4 aq = {0.f, 0.f, 0.f, 0.f}, ak = {0.f, 0.f, 0.f, 0.f};
#pragma unroll
      for (int c = 0; c < 4; ++c) {
        aq = MFMA(x[c], wq[s][c], aq);
        ak = MFMA(x[c], wk[s][c], ak);
      }
      const int cP = n0 >> 1;
      const int Gp = ((n0 & 1) << 1) | (t >> 3);
      const int ep = t & 7;
#pragma unroll
      for (int r = 0; r < 4; ++r) {
        int row = r0s + g * 4 + r;
        size_t qoff = ((size_t)((row >> 4) * 4 + cP) * 64 + ((Gp << 4) | (row & 15))) * 8 + ep;
        qf[qoff] = bfc(aq[r] * 0.015625f);   // fold 1/sqrt(4096)
        int tp = (row & 3) | (((row >> 3) & 3) << 2);
        size_t koff =
            ((size_t)(((row >> 5) * 2 + ((row >> 2) & 1)) * 4 + cP) * 64 + ((Gp << 4) | tp)) * 8 +
            ep;
        kf[koff] = bfc(ak[r]);
      }
    }

    const int key = r0s + t;
    const int kk = key & 31;
    const size_t vbase = (size_t)(key >> 5) * 4096 + (size_t)(kk >> 3) * 128 + (kk & 7);
#pragma unroll
    for (int s = 0; s < 2; ++s) {
      const int u0 = w + s * 4;
      f32x4 av = {0.f, 0.f, 0.f, 0.f};
#pragma unroll
      for (int c = 0; c < 4; ++c)
        av = MFMA(wv[s][c], x[c], av);
#pragma unroll
      for (int r = 0; r < 4; ++r)
        vt[vbase + (size_t)u0 * 512 + (g * 4 + r) * 8] = bfc(av[r]);
    }
  }
}

// ---- flash attention v11: register-direct streaming (the R5/R6/R8 lineage).
// 512 blocks = 2/CU = 2 waves/SIMD. Block = one 32-query group gamma' (0..127
// per batch), batch pinned to an XCD pair, biggest groups dispatched first.
// 4 waves slice 32-key chunks mod 4. All loads contiguous coalesced 1-KB
// streams (vt2). K register-prefetched across the backedge; V loaded at body
// top, consumed after QK+exp. Per-wave footprint ~224 unified regs -> fits the
// 256-reg budget of 2 waves/SIMD (launch_bounds(256,2)) with NO spills.
// Partials add (no online max; |s| <= ~2); staged 4-way LDS combine at end.
__global__ __launch_bounds__(256, 2) void attn_kernel(
    const unsigned short* __restrict__ qf,
    const unsigned short* __restrict__ kf,
    const unsigned short* __restrict__ vt,
    float* __restrict__ out) {
  const int tid = threadIdx.x;
  const int w = tid >> 6, lane = tid & 63;
  const int t = lane & 15, G = lane >> 4;
  const int bi = blockIdx.x;
  const int xcd = bi & 7;                       // assumed round-robin XCD mapping
  const int b = xcd >> 1;                       // batch pinned to an XCD pair
  const int gi = ((bi >> 3) << 1) | (xcd & 1);  // 0..127 within batch
  const int gp = 127 - gi;                      // biggest groups dispatch first
  const int q0 = gp * 32;                       // 32 queries per block
  const int nch = gp + 1;                       // 32-key chunks touching causal region

  const unsigned short* kfb = kf + (size_t)b * 128 * 4096;
  const unsigned short* vtb = vt + (size_t)b * 128 * 4096;

  // Q fragments for tiles 2gp, 2gp+1: 8 coalesced 1-KB loads
  bf16x8 qa[2][4];
#pragma unroll
  for (int X = 0; X < 2; ++X)
#pragma unroll
    for (int c = 0; c < 4; ++c)
      qa[X][c] = ld8(qf + ((size_t)((b * 256 + 2 * gp + X) * 4 + c) * 64 + lane) * 8);

  f32x4 O[2][8];
#pragma unroll
  for (int X = 0; X < 2; ++X)
#pragma unroll
    for (int u0 = 0; u0 < 8; ++u0) O[X][u0] = (f32x4){0.f, 0.f, 0.f, 0.f};
  float ls[2] = {0.f, 0.f};

  int j = w;
  bf16x8 kc[8];
  if (j < nch) {
    const unsigned short* kblk = kfb + (size_t)j * 4096;
#pragma unroll
    for (int ci = 0; ci < 8; ++ci) kc[ci] = ld8(kblk + ci * 512 + lane * 8);
  }

  for (; j < nch; j += 4) {
    // V frags for this chunk: issued first, consumed after QK MFMAs + exp
    const unsigned short* vblk = vtb + (size_t)j * 4096;
    bf16x8 vc[8];
#pragma unroll
    for (int ci = 0; ci < 8; ++ci) vc[ci] = ld8(vblk + ci * 512 + lane * 8);

    // K prefetch for chunk j+4 (covers the whole body)
    const bool hn = (j + 4) < nch;
    bf16x8 kn[8];
    if (hn) {
      const unsigned short* kb2 = kfb + (size_t)(j + 4) * 4096;
#pragma unroll
      for (int ci = 0; ci < 8; ++ci) kn[ci] = ld8(kb2 + ci * 512 + lane * 8);
    }

    // S^T = K Q^T for 32 keys x 32 queries
    f32x4 sA0 = (f32x4){0.f, 0.f, 0.f, 0.f}, sA1 = sA0, sB0 = sA0, sB1 = sA0;
#pragma unroll
    for (int c = 0; c < 4; ++c) {
      sA0 = MFMA(kc[c], qa[0][c], sA0);
      sA1 = MFMA(kc[4 + c], qa[0][c], sA1);
      sB0 = MFMA(kc[c], qa[1][c], sB0);
      sB1 = MFMA(kc[4 + c], qa[1][c], sB1);
    }

    const int j0 = j * 32;
    bf16x8 pbA, pbB;
    if (j < nch - 1) {  // interior chunk: no mask anywhere
#pragma unroll
      for (int r = 0; r < 4; ++r) {
        float a0 = __expf(sA0[r]), a1 = __expf(sA1[r]);
        float b0 = __expf(sB0[r]), b1 = __expf(sB1[r]);
        ls[0] += a0 + a1;
        ls[1] += b0 + b1;
        pbA[r] = (__bf16)a0; pbA[r + 4] = (__bf16)a1;
        pbB[r] = (__bf16)b0; pbB[r + 4] = (__bf16)b1;
      }
    } else {            // diagonal chunk: causal mask
      const int limA = q0 + t, limB = q0 + 16 + t;
#pragma unroll
      for (int r = 0; r < 4; ++r) {
        int k0 = j0 + G * 8 + r;
        float a0 = (k0 <= limA) ? __expf(sA0[r]) : 0.f;
        float a1 = (k0 + 4 <= limA) ? __expf(sA1[r]) : 0.f;
        float b0 = (k0 <= limB) ? __expf(sB0[r]) : 0.f;
        float b1 = (k0 + 4 <= limB) ? __expf(sB1[r]) : 0.f;
        ls[0] += a0 + a1;
        ls[1] += b0 + b1;
        pbA[r] = (__bf16)a0; pbA[r + 4] = (__bf16)a1;
        pbB[r] = (__bf16)b0; pbB[r + 4] = (__bf16)b1;
      }
    }

    // O += P V  (vc[u0] = B[k=G*8+j][n=t] = V[key][u0*16+t] under vt2)
#pragma unroll
    for (int u0 = 0; u0 < 8; ++u0) {
      O[0][u0] = MFMA(pbA, vc[u0], O[0][u0]);
      O[1][u0] = MFMA(pbB, vc[u0], O[1][u0]);
    }

    if (hn) {
#pragma unroll
      for (int ci = 0; ci < 8; ++ci) kc[ci] = kn[ci];
    }
  }

  // staged 4-way combine: one q-tile X at a time (27 KB LDS, partials add)
  __shared__ float cmb[3][64][36];
#pragma unroll 1
  for (int X = 0; X < 2; ++X) {
    __syncthreads();
    if (w > 0) {
#pragma unroll
      for (int u0 = 0; u0 < 8; ++u0)
        *reinterpret_cast<f32x4*>(&cmb[w - 1][lane][u0 * 4]) = O[X][u0];
      cmb[w - 1][lane][32] = ls[X];
    }
    __syncthreads();
    if (w == 0) {
      f32x4 acc[8];
#pragma unroll
      for (int u0 = 0; u0 < 8; ++u0) acc[u0] = O[X][u0];
      float lt = ls[X];
#pragma unroll
      for (int ww = 0; ww < 3; ++ww) {
#pragma unroll
        for (int u0 = 0; u0 < 8; ++u0) {
          f32x4 q4 = *reinterpret_cast<const f32x4*>(&cmb[ww][lane][u0 * 4]);
          acc[u0][0] += q4[0]; acc[u0][1] += q4[1];
          acc[u0][2] += q4[2]; acc[u0][3] += q4[3];
        }
        lt += cmb[ww][lane][32];
      }
      // row sums: lanes {t,t+16,t+32,t+48} hold partials for query t of tile X
      lt += __shfl_xor(lt, 16);
      lt += __shfl_xor(lt, 32);
      float linv[4];
#pragma unroll
      for (int r = 0; r < 4; ++r) linv[r] = 1.0f / __shfl(lt, G * 4 + r);
      float* op = out + ((size_t)(b * T_SEQ + q0 + 16 * X + G * 4)) * DD + t;
#pragma unroll
      for (int u0 = 0; u0 < 8; ++u0)
#pragma unroll
        for (int r = 0; r < 4; ++r)
          op[(size_t)r * DD + u0 * 16] = acc[u0][r] * linv[r];
    }
  }
}

extern "C" void kernel_launch(void* const* d_in, const int* in_sizes, int n_in,
                              void* d_out, int out_size, void* d_ws, size_t ws_size,
                              hipStream_t stream) {
  const float* X  = (const float*)d_in[0];
  const float* Wq = (const float*)d_in[1];
  const float* Wk = (const float*)d_in[2];
  const float* Wv = (const float*)d_in[3];
  float* out = (float*)d_out;

  unsigned short* qf = (unsigned short*)d_ws;          // frag-major Q [BT/16][4][64][8]
  unsigned short* kf = qf + (size_t)BT * DD;            // frag-major K [BT/32][2][4][64][8]
  unsigned short* vt = kf + (size_t)BT * DD;            // vt2 V^T frag layout
  unsigned short* fq = vt + (size_t)BT * DD;            // frag-major W (16384 each)
  unsigned short* fk = fq + DD * DD;
  unsigned short* fv = fk + DD * DD;

  dim3 wt_grid(64, 3);
  wt_kernel<<<wt_grid, 256, 0, stream>>>(Wq, Wk, Wv, fq, fk, fv);
  proj_kernel<<<BT / 32, 256, 0, stream>>>(X, fq, fk, fv, qf, kf, vt);
  attn_kernel<<<512, 256, 0, stream>>>(qf, kf, vt, out);
}